// Round 2
// baseline (2019.286 us; speedup 1.0000x reference)
//
#include <hip/hip_runtime.h>
#include <hip/hip_bf16.h>
#include <math.h>

// ---------------------------------------------------------------------------
// MultiScaleGNN: 3x GAT (single head) -> BiLSTM JK attention -> linear out
// GAT in f32; LSTM GEMMs via bf16 MFMA (f32 accum); nonlinearities f32.
// ---------------------------------------------------------------------------

typedef __attribute__((ext_vector_type(4))) float f32x4;
typedef __attribute__((ext_vector_type(8))) short bf16x8;

__device__ __forceinline__ float sigmoid_f(float x) {
    return 1.0f / (1.0f + __expf(-x));
}
__device__ __forceinline__ float tanh_f(float x) {
    return 2.0f / (1.0f + __expf(-2.0f * x)) - 1.0f;
}
__device__ __forceinline__ unsigned short f2bf(float x) {   // RNE f32->bf16
    union { float f; unsigned int u; } v; v.f = x;
    unsigned int r = (v.u + 0x7FFFu + ((v.u >> 16) & 1u)) >> 16;
    return (unsigned short)r;
}

// ---- GAT: h = x @ W^T ; al = h @ asrc ; ar = h @ adst  (one wave per node) --
template<int K>
__global__ __launch_bounds__(256) void lin_kernel(
    const float* __restrict__ x, const float* __restrict__ W,
    const float* __restrict__ asrc, const float* __restrict__ adst,
    float* __restrict__ h, float* __restrict__ al, float* __restrict__ ar, int N)
{
    __shared__ float Wl[64][K + 1];
    for (int i = threadIdx.x; i < 64 * K; i += 256)
        Wl[i / K][i % K] = W[i];
    __syncthreads();

    int lane = threadIdx.x & 63;
    float as = asrc[lane], ad = adst[lane];
    int wid = (blockIdx.x * 256 + threadIdx.x) >> 6;
    int nw  = (gridDim.x * 256) >> 6;
    for (int n = wid; n < N; n += nw) {
        const float* xr = x + (size_t)n * K;
        float acc = 0.0f;
        #pragma unroll
        for (int k = 0; k < K; k += 4) {
            float4 xv = *reinterpret_cast<const float4*>(xr + k);
            acc += xv.x * Wl[lane][k]     + xv.y * Wl[lane][k + 1]
                 + xv.z * Wl[lane][k + 2] + xv.w * Wl[lane][k + 3];
        }
        h[(size_t)n * 64 + lane] = acc;
        float pa = acc * as, pr = acc * ad;
        #pragma unroll
        for (int off = 32; off > 0; off >>= 1) {
            pa += __shfl_down(pa, off);
            pr += __shfl_down(pr, off);
        }
        if (lane == 0) { al[n] = pa; ar[n] = pr; }
    }
}

// ---- per-layer init: den=0, acc=0 -----------------------------------------
__global__ void init_layer(float* __restrict__ den, float* __restrict__ acc, int N)
{
    int i = blockIdx.x * blockDim.x + threadIdx.x;
    if (i < N * 64) acc[i] = 0.0f;
    if (i < N) den[i] = 0.0f;
}

// ---- fused edge pass (no max subtraction; e is bounded, exp can't overflow)
// one wave per edge: den += exp(e); acc += exp(e)*h[src]
__global__ __launch_bounds__(256) void edge_kernel(
    const int* __restrict__ src, const int* __restrict__ dst,
    const float* __restrict__ al, const float* __restrict__ ar,
    const float* __restrict__ h, float* __restrict__ den,
    float* __restrict__ acc, int E, int N)
{
    int Et = E + N;
    int lane = threadIdx.x & 63;
    int wid = (blockIdx.x * 256 + threadIdx.x) >> 6;
    int nw  = (gridDim.x * 256) >> 6;
    for (int i = wid; i < Et; i += nw) {
        int s = (i < E) ? src[i] : (i - E);
        int d = (i < E) ? dst[i] : (i - E);
        float e = al[s] + ar[d];
        e = (e >= 0.0f) ? e : 0.2f * e;
        float ex = __expf(e);
        if (lane == 0) atomicAdd(&den[d], ex);
        atomicAdd(&acc[(size_t)d * 64 + lane], ex * h[(size_t)s * 64 + lane]);
    }
}

// ---- finalize layer: seq_l = relu(acc/den + b) ----------------------------
__global__ void finalize_kernel(const float* __restrict__ acc,
                                const float* __restrict__ den,
                                const float* __restrict__ b,
                                float* __restrict__ outseq, int N)
{
    int i = blockIdx.x * blockDim.x + threadIdx.x;
    if (i >= N * 64) return;
    int n = i >> 6, j = i & 63;
    float v = acc[i] / den[n] + b[j];
    outseq[i] = fmaxf(v, 0.0f);
}

// ---- LSTM weight prep: bf16 copies in natural [gate j][k] layout ----------
// WB bf16: [dir][ Wih(384*64) | Whh(384*96) ]  (61440 elems/dir)
// bsum f32: [dir][384]
__global__ void prep_lstm(
    const float* __restrict__ WihF, const float* __restrict__ WhhF,
    const float* __restrict__ bihF, const float* __restrict__ bhhF,
    const float* __restrict__ WihB_, const float* __restrict__ WhhB_,
    const float* __restrict__ bihB_, const float* __restrict__ bhhB_,
    unsigned short* __restrict__ WB, float* __restrict__ bsum)
{
    int tid = blockIdx.x * blockDim.x + threadIdx.x;
    if (tid < 2 * 61440) {
        int dir = tid / 61440, r = tid % 61440;
        const float* Wih = dir ? WihB_ : WihF;
        const float* Whh = dir ? WhhB_ : WhhF;
        float v = (r < 24576) ? Wih[r] : Whh[r - 24576];
        WB[tid] = f2bf(v);
    } else if (tid < 2 * 61440 + 2 * 384) {
        int q = tid - 2 * 61440;
        int dir = q / 384, j = q % 384;
        bsum[q] = dir ? (bihB_[j] + bhhB_[j]) : (bihF[j] + bhhF[j]);
    }
}

// ---- fused BiLSTM (MFMA) + JK attention + output projection ---------------
// Block = 4 waves, 64 nodes. Wave w owns M-tile w (nodes 16w..16w+15) and all
// 24 gate tiles -> c is thread-private, hs rows are wave-private: the entire
// recurrent loop needs NO __syncthreads.
// MFMA frag convention (self-consistent A/B k-map): lane l, i16=l&15, g=l>>4:
//   A slot s = M[i16][kc*32 + g*8 + s];  B slot s = W[j = tile*16+i16][same k]
//   D: col = lane&15 (gate), row = g*4 + reg (node)   [m89-verified layout]
__global__ __launch_bounds__(256, 2) void lstm_kernel(
    const float* __restrict__ seq, const unsigned short* __restrict__ WB,
    const float* __restrict__ bsum, const float* __restrict__ attW,
    const float* __restrict__ attb, const float* __restrict__ outW,
    const float* __restrict__ outb, float* __restrict__ out, int N)
{
    __shared__ unsigned short xs[3][64][72];   // seq tiles bf16 (+8 pad)
    __shared__ unsigned short hs[64][104];     // hidden state bf16 (+8 pad)
    __shared__ float logit[3][64];

    const int tid  = threadIdx.x;
    const int lane = tid & 63;
    const int w    = tid >> 6;        // wave id == M-tile
    const int i16  = lane & 15;
    const int g    = lane >> 4;
    const int n0   = blockIdx.x * 64;
    const int nodebase = 16 * w;
    const int myrow = nodebase + g * 4;   // + reg

    for (int idx = tid; idx < 3 * 64 * 64; idx += 256) {
        int t = idx >> 12, r = (idx >> 6) & 63, k = idx & 63;
        int n = n0 + r;
        float v = (n < N) ? seq[((size_t)t * N + n) * 64 + k] : 0.0f;
        xs[t][r][k] = f2bf(v);
    }
    float attb0 = attb[0];
    if (lane < 48) logit[lane >> 4][nodebase + i16] = attb0;
    __syncthreads();

    for (int dir = 0; dir < 2; ++dir) {
        const unsigned short* Wih = WB + dir * 61440;
        const unsigned short* Whh = Wih + 24576;
        const float* bs = bsum + dir * 384;
        const float* aw = attW + dir * 96;

        // zero this wave's hs rows (wave-private, no barrier needed)
        for (int e = lane; e < 16 * 48; e += 64) {
            int r = e / 48, c2 = e % 48;
            *reinterpret_cast<unsigned int*>(&hs[nodebase + r][c2 * 2]) = 0u;
        }

        float c[6][4];
        #pragma unroll
        for (int a = 0; a < 6; ++a)
            #pragma unroll
            for (int b = 0; b < 4; ++b) c[a][b] = 0.0f;

        float awr[6];
        #pragma unroll
        for (int t6 = 0; t6 < 6; ++t6) awr[t6] = aw[t6 * 16 + i16];

        for (int step = 0; step < 3; ++step) {
            int t = dir ? (2 - step) : step;

            f32x4 acc[6][4];
            #pragma unroll
            for (int t6 = 0; t6 < 6; ++t6)
                #pragma unroll
                for (int q = 0; q < 4; ++q) {
                    float bv = bs[q * 96 + t6 * 16 + i16];
                    acc[t6][q] = (f32x4){bv, bv, bv, bv};
                }

            // G += X(t) @ Wih^T   (K = 64)
            #pragma unroll
            for (int kc = 0; kc < 2; ++kc) {
                bf16x8 af = *reinterpret_cast<const bf16x8*>(
                    &xs[t][nodebase + i16][kc * 32 + g * 8]);
                #pragma unroll
                for (int t6 = 0; t6 < 6; ++t6)
                    #pragma unroll
                    for (int q = 0; q < 4; ++q) {
                        int j = q * 96 + t6 * 16 + i16;
                        bf16x8 bfr = *reinterpret_cast<const bf16x8*>(
                            &Wih[j * 64 + kc * 32 + g * 8]);
                        acc[t6][q] = __builtin_amdgcn_mfma_f32_16x16x32_bf16(
                            af, bfr, acc[t6][q], 0, 0, 0);
                    }
            }
            // G += H @ Whh^T   (K = 96)
            #pragma unroll
            for (int kc = 0; kc < 3; ++kc) {
                bf16x8 af = *reinterpret_cast<const bf16x8*>(
                    &hs[nodebase + i16][kc * 32 + g * 8]);
                #pragma unroll
                for (int t6 = 0; t6 < 6; ++t6)
                    #pragma unroll
                    for (int q = 0; q < 4; ++q) {
                        int j = q * 96 + t6 * 16 + i16;
                        bf16x8 bfr = *reinterpret_cast<const bf16x8*>(
                            &Whh[j * 96 + kc * 32 + g * 8]);
                        acc[t6][q] = __builtin_amdgcn_mfma_f32_16x16x32_bf16(
                            af, bfr, acc[t6][q], 0, 0, 0);
                    }
            }

            // nonlinearities + h write (wave-private rows) + logit partials
            float lp[4] = {0.0f, 0.0f, 0.0f, 0.0f};
            #pragma unroll
            for (int t6 = 0; t6 < 6; ++t6) {
                #pragma unroll
                for (int reg = 0; reg < 4; ++reg) {
                    float ii = acc[t6][0][reg];
                    float ff = acc[t6][1][reg];
                    float gg = acc[t6][2][reg];
                    float oo = acc[t6][3][reg];
                    float cn = sigmoid_f(ff) * c[t6][reg]
                             + sigmoid_f(ii) * tanh_f(gg);
                    c[t6][reg] = cn;
                    float hn = sigmoid_f(oo) * tanh_f(cn);
                    hs[myrow + reg][t6 * 16 + i16] = f2bf(hn);
                    lp[reg] += hn * awr[t6];
                }
            }
            #pragma unroll
            for (int reg = 0; reg < 4; ++reg) {
                float v = lp[reg];
                v += __shfl_xor(v, 1);
                v += __shfl_xor(v, 2);
                v += __shfl_xor(v, 4);
                v += __shfl_xor(v, 8);
                if (i16 == 0) logit[t][myrow + reg] += v;
            }
        }
    }
    __syncthreads();

    // alpha = softmax over the 3 layers
    if (w == 0) {
        float l0 = logit[0][lane], l1 = logit[1][lane], l2 = logit[2][lane];
        float mx = fmaxf(fmaxf(l0, l1), l2);
        float e0 = __expf(l0 - mx), e1 = __expf(l1 - mx), e2 = __expf(l2 - mx);
        float inv = 1.0f / (e0 + e1 + e2);
        logit[0][lane] = e0 * inv; logit[1][lane] = e1 * inv; logit[2][lane] = e2 * inv;
    }
    __syncthreads();

    // agg[n][k] = sum_t alpha[t][n] * seq_f32[t][n][k]  (alias over dead xs)
    float (*agg)[68] = reinterpret_cast<float(*)[68]>(&xs[0][0][0]);
    for (int idx = tid; idx < 64 * 64; idx += 256) {
        int r = idx >> 6, k = idx & 63;
        int n = n0 + r;
        float v = 0.0f;
        if (n < N) {
            float a0 = logit[0][r], a1 = logit[1][r], a2 = logit[2][r];
            v = a0 * seq[((size_t)n) * 64 + k]
              + a1 * seq[((size_t)N + n) * 64 + k]
              + a2 * seq[((size_t)2 * N + n) * 64 + k];
        }
        agg[r][k] = v;
    }
    __syncthreads();

    // out[n][j] = agg[n] . outW[j] + outb[j]
    float ob = outb[lane];
    const float* owr = outW + (size_t)lane * 64;
    for (int r = w; r < 64; r += 4) {
        int n = n0 + r;
        if (n >= N) break;
        float a = 0.0f;
        #pragma unroll
        for (int k = 0; k < 64; ++k) a += agg[r][k] * owr[k];
        out[(size_t)n * 64 + lane] = a + ob;
    }
}

// ---------------------------------------------------------------------------
extern "C" void kernel_launch(void* const* d_in, const int* in_sizes, int n_in,
                              void* d_out, int out_size, void* d_ws, size_t ws_size,
                              hipStream_t stream)
{
    const float* x    = (const float*)d_in[0];
    const int*   ei   = (const int*)d_in[1];
    const float* convW[3]  = {(const float*)d_in[2], (const float*)d_in[6],  (const float*)d_in[10]};
    const float* convAs[3] = {(const float*)d_in[3], (const float*)d_in[7],  (const float*)d_in[11]};
    const float* convAd[3] = {(const float*)d_in[4], (const float*)d_in[8],  (const float*)d_in[12]};
    const float* convB[3]  = {(const float*)d_in[5], (const float*)d_in[9],  (const float*)d_in[13]};
    const float* WihF = (const float*)d_in[14];
    const float* WhhF = (const float*)d_in[15];
    const float* bihF = (const float*)d_in[16];
    const float* bhhF = (const float*)d_in[17];
    const float* WihB = (const float*)d_in[18];
    const float* WhhB = (const float*)d_in[19];
    const float* bihB = (const float*)d_in[20];
    const float* bhhB = (const float*)d_in[21];
    const float* attW = (const float*)d_in[22];
    const float* attb = (const float*)d_in[23];
    const float* outW = (const float*)d_in[24];
    const float* outb = (const float*)d_in[25];

    int N = in_sizes[0] / 128;
    int E = in_sizes[1] / 2;
    const int* src = ei;
    const int* dst = ei + E;

    float* w = (float*)d_ws;
    float* seq  = w;  w += (size_t)3 * N * 64;
    float* h_ws = w;  w += (size_t)N * 64;
    float* acc  = w;  w += (size_t)N * 64;
    float* al   = w;  w += N;
    float* ar   = w;  w += N;
    float* den  = w;  w += N;
    float* bsum = w;  w += 768;
    unsigned short* WB = (unsigned short*)w;   // 122880 bf16

    prep_lstm<<<(2 * 61440 + 768 + 255) / 256, 256, 0, stream>>>(
        WihF, WhhF, bihF, bhhF, WihB, WhhB, bihB, bhhB, WB, bsum);

    int nb_nodes = (N * 64 + 255) / 256;
    for (int l = 0; l < 3; ++l) {
        const float* in = (l == 0) ? x : seq + (size_t)(l - 1) * N * 64;
        if (l == 0)
            lin_kernel<128><<<2048, 256, 0, stream>>>(in, convW[l], convAs[l], convAd[l],
                                                      h_ws, al, ar, N);
        else
            lin_kernel<64><<<2048, 256, 0, stream>>>(in, convW[l], convAs[l], convAd[l],
                                                     h_ws, al, ar, N);
        init_layer<<<nb_nodes, 256, 0, stream>>>(den, acc, N);
        edge_kernel<<<16384, 256, 0, stream>>>(src, dst, al, ar, h_ws, den, acc, E, N);
        finalize_kernel<<<nb_nodes, 256, 0, stream>>>(acc, den, convB[l],
                                                      seq + (size_t)l * N * 64, N);
    }

    lstm_kernel<<<(N + 63) / 64, 256, 0, stream>>>(seq, WB, bsum, attW, attb,
                                                   outW, outb, (float*)d_out, N);
}

// Round 3
// 1650.373 us; speedup vs baseline: 1.2235x; 1.2235x over previous
//
#include <hip/hip_runtime.h>
#include <hip/hip_bf16.h>
#include <math.h>

// ---------------------------------------------------------------------------
// MultiScaleGNN: 3x GAT (single head) -> BiLSTM JK attention -> linear out
// GAT in f32; LSTM GEMMs via bf16 MFMA (f32 accum); nonlinearities f32.
// ---------------------------------------------------------------------------

typedef __attribute__((ext_vector_type(4))) float f32x4;
typedef __attribute__((ext_vector_type(8))) short bf16x8;

__device__ __forceinline__ float sigmoid_f(float x) {
    return 1.0f / (1.0f + __expf(-x));
}
__device__ __forceinline__ float tanh_f(float x) {
    return 2.0f / (1.0f + __expf(-2.0f * x)) - 1.0f;
}
__device__ __forceinline__ unsigned short f2bf(float x) {   // RNE f32->bf16
    union { float f; unsigned int u; } v; v.f = x;
    unsigned int r = (v.u + 0x7FFFu + ((v.u >> 16) & 1u)) >> 16;
    return (unsigned short)r;
}

// ---- GAT: h = x @ W^T ; al = h @ asrc ; ar = h @ adst  (one wave per node) --
// x-row pointer made wave-uniform via readfirstlane -> scalar s_load path.
template<int K>
__global__ __launch_bounds__(256) void lin_kernel(
    const float* __restrict__ x, const float* __restrict__ W,
    const float* __restrict__ asrc, const float* __restrict__ adst,
    float* __restrict__ h, float* __restrict__ al, float* __restrict__ ar, int N)
{
    __shared__ __align__(16) float Wl[64][K + 4];
    for (int i = threadIdx.x; i < 64 * K; i += 256)
        Wl[i / K][i % K] = W[i];
    __syncthreads();

    int lane = threadIdx.x & 63;
    float as = asrc[lane], ad = adst[lane];
    int wid = (blockIdx.x * 256 + threadIdx.x) >> 6;
    int nw  = (gridDim.x * 256) >> 6;
    for (int n = wid; n < N; n += nw) {
        int nu = __builtin_amdgcn_readfirstlane(n);      // certify uniform
        const float* xr = x + (size_t)nu * K;
        float acc = 0.0f;
        #pragma unroll
        for (int k = 0; k < K; k += 4) {
            float4 xv = *reinterpret_cast<const float4*>(xr + k);
            f32x4 wv = *reinterpret_cast<const f32x4*>(&Wl[lane][k]);
            acc += xv.x * wv.x + xv.y * wv.y + xv.z * wv.z + xv.w * wv.w;
        }
        h[(size_t)nu * 64 + lane] = acc;
        float pa = acc * as, pr = acc * ad;
        #pragma unroll
        for (int off = 32; off > 0; off >>= 1) {
            pa += __shfl_down(pa, off);
            pr += __shfl_down(pr, off);
        }
        if (lane == 0) { al[nu] = pa; ar[nu] = pr; }
    }
}

// ---- per-layer init: den=0, acc=0 -----------------------------------------
__global__ void init_layer(float* __restrict__ den, float* __restrict__ acc, int N)
{
    int i = blockIdx.x * blockDim.x + threadIdx.x;
    if (i < N * 64) acc[i] = 0.0f;
    if (i < N) den[i] = 0.0f;
}

// ---- fused edge pass (no max subtraction; e is bounded, exp can't overflow)
__global__ __launch_bounds__(256) void edge_kernel(
    const int* __restrict__ src, const int* __restrict__ dst,
    const float* __restrict__ al, const float* __restrict__ ar,
    const float* __restrict__ h, float* __restrict__ den,
    float* __restrict__ acc, int E, int N)
{
    int Et = E + N;
    int lane = threadIdx.x & 63;
    int wid = (blockIdx.x * 256 + threadIdx.x) >> 6;
    int nw  = (gridDim.x * 256) >> 6;
    for (int i = wid; i < Et; i += nw) {
        int s = (i < E) ? src[i] : (i - E);
        int d = (i < E) ? dst[i] : (i - E);
        float e = al[s] + ar[d];
        e = (e >= 0.0f) ? e : 0.2f * e;
        float ex = __expf(e);
        if (lane == 0) atomicAdd(&den[d], ex);
        atomicAdd(&acc[(size_t)d * 64 + lane], ex * h[(size_t)s * 64 + lane]);
    }
}

// ---- finalize layer: seq_l = relu(acc/den + b) ----------------------------
__global__ void finalize_kernel(const float* __restrict__ acc,
                                const float* __restrict__ den,
                                const float* __restrict__ b,
                                float* __restrict__ outseq, int N)
{
    int i = blockIdx.x * blockDim.x + threadIdx.x;
    if (i >= N * 64) return;
    int n = i >> 6, j = i & 63;
    float v = acc[i] / den[n] + b[j];
    outseq[i] = fmaxf(v, 0.0f);
}

// ---- LSTM weight prep: bf16 copies in natural [gate j][k] layout ----------
// WB bf16: [dir][ Wih(384*64) | Whh(384*96) ]  (61440 elems/dir)
// bsum f32: [dir][384]
__global__ void prep_lstm(
    const float* __restrict__ WihF, const float* __restrict__ WhhF,
    const float* __restrict__ bihF, const float* __restrict__ bhhF,
    const float* __restrict__ WihB_, const float* __restrict__ WhhB_,
    const float* __restrict__ bihB_, const float* __restrict__ bhhB_,
    unsigned short* __restrict__ WB, float* __restrict__ bsum)
{
    int tid = blockIdx.x * blockDim.x + threadIdx.x;
    if (tid < 2 * 61440) {
        int dir = tid / 61440, r = tid % 61440;
        const float* Wih = dir ? WihB_ : WihF;
        const float* Whh = dir ? WhhB_ : WhhF;
        float v = (r < 24576) ? Wih[r] : Whh[r - 24576];
        WB[tid] = f2bf(v);
    } else if (tid < 2 * 61440 + 2 * 384) {
        int q = tid - 2 * 61440;
        int dir = q / 384, j = q % 384;
        bsum[q] = dir ? (bihB_[j] + bhhB_[j]) : (bihF[j] + bhhF[j]);
    }
}

// ---- fused BiLSTM (MFMA) + JK attention + output projection ---------------
// Block = 4 waves, 64 nodes. Wave w owns M-tile w (nodes 16w..16w+15) and all
// gate tiles; c is thread-private, hs rows are wave-private -> no barriers in
// the recurrent loop. Accumulator live-range = ONE u-tile (t6) => no spill.
// Frag convention (verified r2, absmax 3.9e-3): lane l, i16=l&15, g=l>>4:
//   A slot s = M[i16][kc*32+g*8+s]; B slot s = W[j][same k], j=q*96+t6*16+i16
//   D: col=i16 (gate channel), row=g*4+reg (node)
__global__ __launch_bounds__(256, 2) void lstm_kernel(
    const float* __restrict__ seq, const unsigned short* __restrict__ WB,
    const float* __restrict__ bsum, const float* __restrict__ attW,
    const float* __restrict__ attb, const float* __restrict__ outW,
    const float* __restrict__ outb, float* __restrict__ out, int N)
{
    __shared__ __align__(16) unsigned short xs[3][64][72];   // seq tiles bf16
    __shared__ __align__(16) unsigned short hs[64][104];     // hidden bf16
    __shared__ float logit[3][64];

    const int tid  = threadIdx.x;
    const int lane = tid & 63;
    const int w    = tid >> 6;
    const int i16  = lane & 15;
    const int g    = lane >> 4;
    const int n0   = blockIdx.x * 64;
    const int nodebase = 16 * w;
    const int myrow = nodebase + g * 4;

    for (int idx = tid; idx < 3 * 64 * 64; idx += 256) {
        int t = idx >> 12, r = (idx >> 6) & 63, k = idx & 63;
        int n = n0 + r;
        float v = (n < N) ? seq[((size_t)t * N + n) * 64 + k] : 0.0f;
        xs[t][r][k] = f2bf(v);
    }
    float attb0 = attb[0];
    if (lane < 48) logit[lane >> 4][nodebase + i16] = attb0;
    __syncthreads();

    for (int dir = 0; dir < 2; ++dir) {
        const unsigned short* Wih = WB + dir * 61440;
        const unsigned short* Whh = Wih + 24576;
        const float* bs = bsum + dir * 384;
        const float* aw = attW + dir * 96;

        // zero this wave's hs rows (wave-private)
        for (int e = lane; e < 16 * 48; e += 64) {
            int r = e / 48, c2 = e % 48;
            *reinterpret_cast<unsigned int*>(&hs[nodebase + r][c2 * 2]) = 0u;
        }

        float c[6][4];
        #pragma unroll
        for (int a = 0; a < 6; ++a)
            #pragma unroll
            for (int b = 0; b < 4; ++b) c[a][b] = 0.0f;

        float awr[6];
        #pragma unroll
        for (int t6 = 0; t6 < 6; ++t6) awr[t6] = aw[t6 * 16 + i16];

        for (int step = 0; step < 3; ++step) {
            int t = dir ? (2 - step) : step;

            // A fragments for this step (20 VGPRs, reused by all t6)
            const unsigned short* xrow = &xs[t][nodebase + i16][0];
            bf16x8 ax0 = *reinterpret_cast<const bf16x8*>(xrow + g * 8);
            bf16x8 ax1 = *reinterpret_cast<const bf16x8*>(xrow + 32 + g * 8);
            const unsigned short* hrow = &hs[nodebase + i16][0];
            bf16x8 ah0 = *reinterpret_cast<const bf16x8*>(hrow + g * 8);
            bf16x8 ah1 = *reinterpret_cast<const bf16x8*>(hrow + 32 + g * 8);
            bf16x8 ah2 = *reinterpret_cast<const bf16x8*>(hrow + 64 + g * 8);

            float lp[4] = {0.0f, 0.0f, 0.0f, 0.0f};
            #pragma unroll
            for (int t6 = 0; t6 < 6; ++t6) {
                const int jb = t6 * 16 + i16;
                f32x4 acc4[4];
                #pragma unroll
                for (int q = 0; q < 4; ++q) {
                    float bv = bs[q * 96 + jb];
                    acc4[q] = (f32x4){bv, bv, bv, bv};
                }
                #pragma unroll
                for (int q = 0; q < 4; ++q) {
                    const unsigned short* wih = Wih + (q * 96 + jb) * 64 + g * 8;
                    const unsigned short* whh = Whh + (q * 96 + jb) * 96 + g * 8;
                    acc4[q] = __builtin_amdgcn_mfma_f32_16x16x32_bf16(
                        ax0, *reinterpret_cast<const bf16x8*>(wih), acc4[q], 0, 0, 0);
                    acc4[q] = __builtin_amdgcn_mfma_f32_16x16x32_bf16(
                        ax1, *reinterpret_cast<const bf16x8*>(wih + 32), acc4[q], 0, 0, 0);
                    acc4[q] = __builtin_amdgcn_mfma_f32_16x16x32_bf16(
                        ah0, *reinterpret_cast<const bf16x8*>(whh), acc4[q], 0, 0, 0);
                    acc4[q] = __builtin_amdgcn_mfma_f32_16x16x32_bf16(
                        ah1, *reinterpret_cast<const bf16x8*>(whh + 32), acc4[q], 0, 0, 0);
                    acc4[q] = __builtin_amdgcn_mfma_f32_16x16x32_bf16(
                        ah2, *reinterpret_cast<const bf16x8*>(whh + 64), acc4[q], 0, 0, 0);
                }
                #pragma unroll
                for (int reg = 0; reg < 4; ++reg) {
                    float ii = acc4[0][reg];
                    float ff = acc4[1][reg];
                    float gg = acc4[2][reg];
                    float oo = acc4[3][reg];
                    float cn = sigmoid_f(ff) * c[t6][reg]
                             + sigmoid_f(ii) * tanh_f(gg);
                    c[t6][reg] = cn;
                    float hn = sigmoid_f(oo) * tanh_f(cn);
                    hs[myrow + reg][jb] = f2bf(hn);
                    lp[reg] += hn * awr[t6];
                }
            }
            #pragma unroll
            for (int reg = 0; reg < 4; ++reg) {
                float v = lp[reg];
                v += __shfl_xor(v, 1);
                v += __shfl_xor(v, 2);
                v += __shfl_xor(v, 4);
                v += __shfl_xor(v, 8);
                if (i16 == 0) logit[t][myrow + reg] += v;
            }
        }
    }
    __syncthreads();

    // alpha = softmax over the 3 layers
    if (w == 0) {
        float l0 = logit[0][lane], l1 = logit[1][lane], l2 = logit[2][lane];
        float mx = fmaxf(fmaxf(l0, l1), l2);
        float e0 = __expf(l0 - mx), e1 = __expf(l1 - mx), e2 = __expf(l2 - mx);
        float inv = 1.0f / (e0 + e1 + e2);
        logit[0][lane] = e0 * inv; logit[1][lane] = e1 * inv; logit[2][lane] = e2 * inv;
    }
    __syncthreads();

    // agg[n][k] = sum_t alpha[t][n] * seq_f32[t][n][k]  (alias over dead xs)
    float (*agg)[68] = reinterpret_cast<float(*)[68]>(&xs[0][0][0]);
    for (int idx = tid; idx < 64 * 64; idx += 256) {
        int r = idx >> 6, k = idx & 63;
        int n = n0 + r;
        float v = 0.0f;
        if (n < N) {
            float a0 = logit[0][r], a1 = logit[1][r], a2 = logit[2][r];
            v = a0 * seq[((size_t)n) * 64 + k]
              + a1 * seq[((size_t)N + n) * 64 + k]
              + a2 * seq[((size_t)2 * N + n) * 64 + k];
        }
        agg[r][k] = v;
    }
    __syncthreads();

    // out[n][j] = agg[n] . outW[j] + outb[j]; outW row held in 64 VGPRs
    f32x4 ow[16];
    #pragma unroll
    for (int kk = 0; kk < 16; ++kk)
        ow[kk] = *reinterpret_cast<const f32x4*>(&outW[(size_t)lane * 64 + kk * 4]);
    float ob = outb[lane];
    for (int r = w; r < 64; r += 4) {
        int n = n0 + r;
        if (n >= N) break;
        float a = ob;
        #pragma unroll
        for (int kk = 0; kk < 16; ++kk) {
            f32x4 av = *reinterpret_cast<const f32x4*>(&agg[r][kk * 4]);
            a += ow[kk].x * av.x + ow[kk].y * av.y
               + ow[kk].z * av.z + ow[kk].w * av.w;
        }
        out[(size_t)n * 64 + lane] = a;
    }
}

// ---------------------------------------------------------------------------
extern "C" void kernel_launch(void* const* d_in, const int* in_sizes, int n_in,
                              void* d_out, int out_size, void* d_ws, size_t ws_size,
                              hipStream_t stream)
{
    const float* x    = (const float*)d_in[0];
    const int*   ei   = (const int*)d_in[1];
    const float* convW[3]  = {(const float*)d_in[2], (const float*)d_in[6],  (const float*)d_in[10]};
    const float* convAs[3] = {(const float*)d_in[3], (const float*)d_in[7],  (const float*)d_in[11]};
    const float* convAd[3] = {(const float*)d_in[4], (const float*)d_in[8],  (const float*)d_in[12]};
    const float* convB[3]  = {(const float*)d_in[5], (const float*)d_in[9],  (const float*)d_in[13]};
    const float* WihF = (const float*)d_in[14];
    const float* WhhF = (const float*)d_in[15];
    const float* bihF = (const float*)d_in[16];
    const float* bhhF = (const float*)d_in[17];
    const float* WihB = (const float*)d_in[18];
    const float* WhhB = (const float*)d_in[19];
    const float* bihB = (const float*)d_in[20];
    const float* bhhB = (const float*)d_in[21];
    const float* attW = (const float*)d_in[22];
    const float* attb = (const float*)d_in[23];
    const float* outW = (const float*)d_in[24];
    const float* outb = (const float*)d_in[25];

    int N = in_sizes[0] / 128;
    int E = in_sizes[1] / 2;
    const int* src = ei;
    const int* dst = ei + E;

    float* w = (float*)d_ws;
    float* seq  = w;  w += (size_t)3 * N * 64;
    float* h_ws = w;  w += (size_t)N * 64;
    float* acc  = w;  w += (size_t)N * 64;
    float* al   = w;  w += N;
    float* ar   = w;  w += N;
    float* den  = w;  w += N;
    float* bsum = w;  w += 768;
    unsigned short* WB = (unsigned short*)w;   // 122880 bf16 (16B-aligned)

    prep_lstm<<<(2 * 61440 + 768 + 255) / 256, 256, 0, stream>>>(
        WihF, WhhF, bihF, bhhF, WihB, WhhB, bihB, bhhB, WB, bsum);

    int nb_nodes = (N * 64 + 255) / 256;
    for (int l = 0; l < 3; ++l) {
        const float* in = (l == 0) ? x : seq + (size_t)(l - 1) * N * 64;
        if (l == 0)
            lin_kernel<128><<<2048, 256, 0, stream>>>(in, convW[l], convAs[l], convAd[l],
                                                      h_ws, al, ar, N);
        else
            lin_kernel<64><<<2048, 256, 0, stream>>>(in, convW[l], convAs[l], convAd[l],
                                                     h_ws, al, ar, N);
        init_layer<<<nb_nodes, 256, 0, stream>>>(den, acc, N);
        edge_kernel<<<16384, 256, 0, stream>>>(src, dst, al, ar, h_ws, den, acc, E, N);
        finalize_kernel<<<nb_nodes, 256, 0, stream>>>(acc, den, convB[l],
                                                      seq + (size_t)l * N * 64, N);
    }

    lstm_kernel<<<(N + 63) / 64, 256, 0, stream>>>(seq, WB, bsum, attW, attb,
                                                   outW, outb, (float*)d_out, N);
}

// Round 4
// 1106.497 us; speedup vs baseline: 1.8249x; 1.4915x over previous
//
#include <hip/hip_runtime.h>
#include <hip/hip_bf16.h>
#include <math.h>

// ---------------------------------------------------------------------------
// MultiScaleGNN: 3x GAT (single head) -> BiLSTM JK attention -> linear out
// GAT in f32; LSTM GEMMs via bf16 MFMA (f32 accum, weights LDS-resident).
// ---------------------------------------------------------------------------

typedef __attribute__((ext_vector_type(4))) float f32x4;
typedef __attribute__((ext_vector_type(8))) short bf16x8;

__device__ __forceinline__ float sigmoid_f(float x) {
    return 1.0f / (1.0f + __expf(-x));
}
__device__ __forceinline__ float tanh_f(float x) {
    return 2.0f / (1.0f + __expf(-2.0f * x)) - 1.0f;
}
__device__ __forceinline__ unsigned short f2bf(float x) {   // RNE f32->bf16
    union { float f; unsigned int u; } v; v.f = x;
    unsigned int r = (v.u + 0x7FFFu + ((v.u >> 16) & 1u)) >> 16;
    return (unsigned short)r;
}

// ---- GAT: h = x @ W^T ; al = h @ asrc ; ar = h @ adst  (one wave per node) --
template<int K>
__global__ __launch_bounds__(256) void lin_kernel(
    const float* __restrict__ x, const float* __restrict__ W,
    const float* __restrict__ asrc, const float* __restrict__ adst,
    float* __restrict__ h, float* __restrict__ al, float* __restrict__ ar, int N)
{
    __shared__ __align__(16) float Wl[64][K + 4];
    for (int i = threadIdx.x; i < 64 * K; i += 256)
        Wl[i / K][i % K] = W[i];
    __syncthreads();

    int lane = threadIdx.x & 63;
    float as = asrc[lane], ad = adst[lane];
    int wid = (blockIdx.x * 256 + threadIdx.x) >> 6;
    int nw  = (gridDim.x * 256) >> 6;
    for (int n = wid; n < N; n += nw) {
        int nu = __builtin_amdgcn_readfirstlane(n);      // certify uniform
        const float* xr = x + (size_t)nu * K;
        float acc = 0.0f;
        #pragma unroll
        for (int k = 0; k < K; k += 4) {
            float4 xv = *reinterpret_cast<const float4*>(xr + k);
            f32x4 wv = *reinterpret_cast<const f32x4*>(&Wl[lane][k]);
            acc += xv.x * wv.x + xv.y * wv.y + xv.z * wv.z + xv.w * wv.w;
        }
        h[(size_t)nu * 64 + lane] = acc;
        float pa = acc * as, pr = acc * ad;
        #pragma unroll
        for (int off = 32; off > 0; off >>= 1) {
            pa += __shfl_down(pa, off);
            pr += __shfl_down(pr, off);
        }
        if (lane == 0) { al[nu] = pa; ar[nu] = pr; }
    }
}

// ---- per-layer init: den=0, acc=0 -----------------------------------------
__global__ void init_layer(float* __restrict__ den, float* __restrict__ acc, int N)
{
    int i = blockIdx.x * blockDim.x + threadIdx.x;
    if (i < N * 64) acc[i] = 0.0f;
    if (i < N) den[i] = 0.0f;
}

// ---- fused edge pass (no max subtraction; e is bounded, exp can't overflow)
__global__ __launch_bounds__(256) void edge_kernel(
    const int* __restrict__ src, const int* __restrict__ dst,
    const float* __restrict__ al, const float* __restrict__ ar,
    const float* __restrict__ h, float* __restrict__ den,
    float* __restrict__ acc, int E, int N)
{
    int Et = E + N;
    int lane = threadIdx.x & 63;
    int wid = (blockIdx.x * 256 + threadIdx.x) >> 6;
    int nw  = (gridDim.x * 256) >> 6;
    for (int i = wid; i < Et; i += nw) {
        int s = (i < E) ? src[i] : (i - E);
        int d = (i < E) ? dst[i] : (i - E);
        float e = al[s] + ar[d];
        e = (e >= 0.0f) ? e : 0.2f * e;
        float ex = __expf(e);
        if (lane == 0) atomicAdd(&den[d], ex);
        atomicAdd(&acc[(size_t)d * 64 + lane], ex * h[(size_t)s * 64 + lane]);
    }
}

// ---- finalize layer: seq_l = relu(acc/den + b) ----------------------------
__global__ void finalize_kernel(const float* __restrict__ acc,
                                const float* __restrict__ den,
                                const float* __restrict__ b,
                                float* __restrict__ outseq, int N)
{
    int i = blockIdx.x * blockDim.x + threadIdx.x;
    if (i >= N * 64) return;
    int n = i >> 6, j = i & 63;
    float v = acc[i] / den[n] + b[j];
    outseq[i] = fmaxf(v, 0.0f);
}

// ---- LSTM weight prep: bf16, FRAGMENT-LANE-MAJOR order --------------------
// Per dir (61440 bf16): Wih frags f=(q*6+t6)*2+kc (48), Whh frags at +24576,
// f=(q*6+t6)*3+kc (72). Each frag = 512 bf16: [lane][slot], lane=(g<<4)|i16,
// value = W[j = q*96+t6*16+i16][k = kc*32+g*8+slot].
__global__ void prep_lstm(
    const float* __restrict__ WihF, const float* __restrict__ WhhF,
    const float* __restrict__ bihF, const float* __restrict__ bhhF,
    const float* __restrict__ WihB_, const float* __restrict__ WhhB_,
    const float* __restrict__ bihB_, const float* __restrict__ bhhB_,
    unsigned short* __restrict__ WB, float* __restrict__ bsum)
{
    int tid = blockIdx.x * blockDim.x + threadIdx.x;
    if (tid < 2 * 61440) {
        int dir = tid / 61440, rr = tid % 61440;
        const float* Wih = dir ? WihB_ : WihF;
        const float* Whh = dir ? WhhB_ : WhhF;
        float v;
        if (rr < 24576) {
            int f = rr >> 9, l = (rr >> 3) & 63, s = rr & 7;
            int kc = f & 1, qt = f >> 1;
            int q = qt / 6, t6 = qt % 6;
            int j = q * 96 + t6 * 16 + (l & 15);
            int k = kc * 32 + (l >> 4) * 8 + s;
            v = Wih[j * 64 + k];
        } else {
            int rr2 = rr - 24576;
            int f = rr2 >> 9, l = (rr2 >> 3) & 63, s = rr2 & 7;
            int kc = f % 3, qt = f / 3;
            int q = qt / 6, t6 = qt % 6;
            int j = q * 96 + t6 * 16 + (l & 15);
            int k = kc * 32 + (l >> 4) * 8 + s;
            v = Whh[j * 96 + k];
        }
        WB[tid] = f2bf(v);
    } else if (tid < 2 * 61440 + 2 * 384) {
        int q2 = tid - 2 * 61440;
        int dir = q2 / 384, j = q2 % 384;
        bsum[q2] = dir ? (bihB_[j] + bhhB_[j]) : (bihF[j] + bhhF[j]);
    }
}

// ---- fused BiLSTM (MFMA, LDS weights) + JK attention + out projection -----
// LDS map (shorts): [0,61440) W frags (one dir at a time)
//                   [61440,75264) xs stride 72 (row-pad shorts 64..71 hold
//                                 the per-(t,node) logit float)
//                   [75264,81920) hs stride 104 (reused as alpha after loop)
// Exactly 160 KB. 1 block/CU; __launch_bounds__(256,1) -> 512-VGPR budget.
__global__ __launch_bounds__(256, 1) void lstm_kernel(
    const float* __restrict__ seq, const unsigned short* __restrict__ WB,
    const float* __restrict__ bsum, const float* __restrict__ attW,
    const float* __restrict__ attb, const float* __restrict__ outW,
    const float* __restrict__ outb, float* __restrict__ out, int N)
{
    __shared__ __align__(16) unsigned short smem[81920];
    unsigned short* WL = smem;
    unsigned short* XS = smem + 61440;
    unsigned short* HS = smem + 75264;

    const int tid  = threadIdx.x;
    const int lane = tid & 63;
    const int w    = tid >> 6;
    const int i16  = lane & 15;
    const int g    = lane >> 4;
    const int n0   = blockIdx.x * 64;
    const int nodebase = 16 * w;
    const int myrow = nodebase + g * 4;

    // stage xs (bf16) + logits (attb) in xs row-pads
    for (int idx = tid; idx < 3 * 64 * 64; idx += 256) {
        int t = idx >> 12, r = (idx >> 6) & 63, k = idx & 63;
        int n = n0 + r;
        float v = (n < N) ? seq[((size_t)t * N + n) * 64 + k] : 0.0f;
        XS[(t * 64 + r) * 72 + k] = f2bf(v);
    }
    float attb0 = attb[0];
    if (tid < 192)
        *reinterpret_cast<float*>(&XS[tid * 72 + 64]) = attb0;   // (t*64+r)*72+64

    for (int dir = 0; dir < 2; ++dir) {
        __syncthreads();   // xs staged / previous dir's W reads complete
        {   // stage this dir's 120 KB of weight fragments (linear, b128)
            const f32x4* gsrc = reinterpret_cast<const f32x4*>(WB + dir * 61440);
            f32x4* ldst = reinterpret_cast<f32x4*>(WL);
            #pragma unroll
            for (int it = 0; it < 30; ++it)
                ldst[it * 256 + tid] = gsrc[it * 256 + tid];
        }
        // zero this wave's hs rows (wave-private)
        for (int e2 = lane; e2 < 16 * 48; e2 += 64) {
            int r = e2 / 48, c2 = e2 % 48;
            *reinterpret_cast<unsigned int*>(&HS[(nodebase + r) * 104 + c2 * 2]) = 0u;
        }
        const float* bs = bsum + dir * 384;
        const float* aw = attW + dir * 96;
        float bsr[24];
        #pragma unroll
        for (int t6 = 0; t6 < 6; ++t6)
            #pragma unroll
            for (int q = 0; q < 4; ++q)
                bsr[t6 * 4 + q] = bs[q * 96 + t6 * 16 + i16];
        float awr[6];
        #pragma unroll
        for (int t6 = 0; t6 < 6; ++t6) awr[t6] = aw[t6 * 16 + i16];
        float c[24];
        #pragma unroll
        for (int a = 0; a < 24; ++a) c[a] = 0.0f;
        __syncthreads();   // WL visible

        for (int step = 0; step < 3; ++step) {
            int t = dir ? (2 - step) : step;
            const unsigned short* xrow = &XS[((t * 64 + nodebase + i16) * 72)];
            bf16x8 ax0 = *reinterpret_cast<const bf16x8*>(xrow + g * 8);
            bf16x8 ax1 = *reinterpret_cast<const bf16x8*>(xrow + 32 + g * 8);
            const unsigned short* hrow = &HS[(nodebase + i16) * 104];
            bf16x8 ah0 = *reinterpret_cast<const bf16x8*>(hrow + g * 8);
            bf16x8 ah1 = *reinterpret_cast<const bf16x8*>(hrow + 32 + g * 8);
            bf16x8 ah2 = *reinterpret_cast<const bf16x8*>(hrow + 64 + g * 8);
            const unsigned short* wbase = WL + lane * 8;

            float lp[4] = {0.0f, 0.0f, 0.0f, 0.0f};
            #pragma unroll
            for (int t6 = 0; t6 < 6; ++t6) {
                const int jb = t6 * 16 + i16;
                f32x4 acc4[4];
                #pragma unroll
                for (int q = 0; q < 4; ++q) {
                    float bv = bsr[t6 * 4 + q];
                    acc4[q] = (f32x4){bv, bv, bv, bv};
                }
                #pragma unroll
                for (int q = 0; q < 4; ++q) {
                    const int qt = q * 6 + t6;
                    const unsigned short* wih = wbase + (qt * 2) * 512;
                    const unsigned short* whh = wbase + 24576 + (qt * 3) * 512;
                    acc4[q] = __builtin_amdgcn_mfma_f32_16x16x32_bf16(
                        ax0, *reinterpret_cast<const bf16x8*>(wih), acc4[q], 0, 0, 0);
                    acc4[q] = __builtin_amdgcn_mfma_f32_16x16x32_bf16(
                        ax1, *reinterpret_cast<const bf16x8*>(wih + 512), acc4[q], 0, 0, 0);
                    acc4[q] = __builtin_amdgcn_mfma_f32_16x16x32_bf16(
                        ah0, *reinterpret_cast<const bf16x8*>(whh), acc4[q], 0, 0, 0);
                    acc4[q] = __builtin_amdgcn_mfma_f32_16x16x32_bf16(
                        ah1, *reinterpret_cast<const bf16x8*>(whh + 512), acc4[q], 0, 0, 0);
                    acc4[q] = __builtin_amdgcn_mfma_f32_16x16x32_bf16(
                        ah2, *reinterpret_cast<const bf16x8*>(whh + 1024), acc4[q], 0, 0, 0);
                }
                #pragma unroll
                for (int reg = 0; reg < 4; ++reg) {
                    float ii = acc4[0][reg];
                    float ff = acc4[1][reg];
                    float gg = acc4[2][reg];
                    float oo = acc4[3][reg];
                    float cn = sigmoid_f(ff) * c[t6 * 4 + reg]
                             + sigmoid_f(ii) * tanh_f(gg);
                    c[t6 * 4 + reg] = cn;
                    float hn = sigmoid_f(oo) * tanh_f(cn);
                    HS[(myrow + reg) * 104 + jb] = f2bf(hn);
                    lp[reg] += hn * awr[t6];
                }
                // fence: keep each t6's 20 B-frag loads inside its region
                __builtin_amdgcn_sched_barrier(0);
            }
            #pragma unroll
            for (int reg = 0; reg < 4; ++reg) {
                float v = lp[reg];
                v += __shfl_xor(v, 1);
                v += __shfl_xor(v, 2);
                v += __shfl_xor(v, 4);
                v += __shfl_xor(v, 8);
                if (i16 == 0)
                    *reinterpret_cast<float*>(
                        &XS[(t * 64 + myrow + reg) * 72 + 64]) += v;
            }
        }
    }
    __syncthreads();

    // alpha = softmax over the 3 layers (logits live in xs pads)
    float* alphaF = reinterpret_cast<float*>(HS);   // hs is dead now
    if (w == 0) {
        float l0 = *reinterpret_cast<float*>(&XS[(0 * 64 + lane) * 72 + 64]);
        float l1 = *reinterpret_cast<float*>(&XS[(1 * 64 + lane) * 72 + 64]);
        float l2 = *reinterpret_cast<float*>(&XS[(2 * 64 + lane) * 72 + 64]);
        float mx = fmaxf(fmaxf(l0, l1), l2);
        float e0 = __expf(l0 - mx), e1 = __expf(l1 - mx), e2 = __expf(l2 - mx);
        float inv = 1.0f / (e0 + e1 + e2);
        alphaF[lane] = e0 * inv; alphaF[64 + lane] = e1 * inv;
        alphaF[128 + lane] = e2 * inv;
    }
    __syncthreads();

    // agg[n][k] = sum_t alpha[t][n] * seq_f32[t][n][k]  (overwrites xs)
    float* aggF = reinterpret_cast<float*>(XS);     // stride 68 floats
    for (int idx = tid; idx < 64 * 64; idx += 256) {
        int r = idx >> 6, k = idx & 63;
        int n = n0 + r;
        float v = 0.0f;
        if (n < N) {
            float a0 = alphaF[r], a1 = alphaF[64 + r], a2 = alphaF[128 + r];
            v = a0 * seq[((size_t)n) * 64 + k]
              + a1 * seq[((size_t)N + n) * 64 + k]
              + a2 * seq[((size_t)2 * N + n) * 64 + k];
        }
        aggF[r * 68 + k] = v;
    }
    __syncthreads();

    // out[n][j] = agg[n] . outW[j] + outb[j]; outW row held in 64 VGPRs
    f32x4 ow[16];
    #pragma unroll
    for (int kk = 0; kk < 16; ++kk)
        ow[kk] = *reinterpret_cast<const f32x4*>(&outW[(size_t)lane * 64 + kk * 4]);
    float ob = outb[lane];
    for (int r = w; r < 64; r += 4) {
        int n = n0 + r;
        if (n >= N) break;
        float a = ob;
        #pragma unroll
        for (int kk = 0; kk < 16; ++kk) {
            f32x4 av = *reinterpret_cast<const f32x4*>(&aggF[r * 68 + kk * 4]);
            a += ow[kk].x * av.x + ow[kk].y * av.y
               + ow[kk].z * av.z + ow[kk].w * av.w;
        }
        out[(size_t)n * 64 + lane] = a;
    }
}

// ---------------------------------------------------------------------------
extern "C" void kernel_launch(void* const* d_in, const int* in_sizes, int n_in,
                              void* d_out, int out_size, void* d_ws, size_t ws_size,
                              hipStream_t stream)
{
    const float* x    = (const float*)d_in[0];
    const int*   ei   = (const int*)d_in[1];
    const float* convW[3]  = {(const float*)d_in[2], (const float*)d_in[6],  (const float*)d_in[10]};
    const float* convAs[3] = {(const float*)d_in[3], (const float*)d_in[7],  (const float*)d_in[11]};
    const float* convAd[3] = {(const float*)d_in[4], (const float*)d_in[8],  (const float*)d_in[12]};
    const float* convB[3]  = {(const float*)d_in[5], (const float*)d_in[9],  (const float*)d_in[13]};
    const float* WihF = (const float*)d_in[14];
    const float* WhhF = (const float*)d_in[15];
    const float* bihF = (const float*)d_in[16];
    const float* bhhF = (const float*)d_in[17];
    const float* WihB = (const float*)d_in[18];
    const float* WhhB = (const float*)d_in[19];
    const float* bihB = (const float*)d_in[20];
    const float* bhhB = (const float*)d_in[21];
    const float* attW = (const float*)d_in[22];
    const float* attb = (const float*)d_in[23];
    const float* outW = (const float*)d_in[24];
    const float* outb = (const float*)d_in[25];

    int N = in_sizes[0] / 128;
    int E = in_sizes[1] / 2;
    const int* src = ei;
    const int* dst = ei + E;

    float* w = (float*)d_ws;
    float* seq  = w;  w += (size_t)3 * N * 64;
    float* h_ws = w;  w += (size_t)N * 64;
    float* acc  = w;  w += (size_t)N * 64;
    float* al   = w;  w += N;
    float* ar   = w;  w += N;
    float* den  = w;  w += N;
    float* bsum = w;  w += 768;
    unsigned short* WB = (unsigned short*)w;   // 122880 bf16 (16B-aligned)

    prep_lstm<<<(2 * 61440 + 768 + 255) / 256, 256, 0, stream>>>(
        WihF, WhhF, bihF, bhhF, WihB, WhhB, bihB, bhhB, WB, bsum);

    int nb_nodes = (N * 64 + 255) / 256;
    for (int l = 0; l < 3; ++l) {
        const float* in = (l == 0) ? x : seq + (size_t)(l - 1) * N * 64;
        if (l == 0)
            lin_kernel<128><<<2048, 256, 0, stream>>>(in, convW[l], convAs[l], convAd[l],
                                                      h_ws, al, ar, N);
        else
            lin_kernel<64><<<2048, 256, 0, stream>>>(in, convW[l], convAs[l], convAd[l],
                                                     h_ws, al, ar, N);
        init_layer<<<nb_nodes, 256, 0, stream>>>(den, acc, N);
        edge_kernel<<<16384, 256, 0, stream>>>(src, dst, al, ar, h_ws, den, acc, E, N);
        finalize_kernel<<<nb_nodes, 256, 0, stream>>>(acc, den, convB[l],
                                                      seq + (size_t)l * N * 64, N);
    }

    lstm_kernel<<<(N + 63) / 64, 256, 0, stream>>>(seq, WB, bsum, attW, attb,
                                                   outW, outb, (float*)d_out, N);
}

// Round 5
// 604.672 us; speedup vs baseline: 3.3395x; 1.8299x over previous
//
#include <hip/hip_runtime.h>
#include <hip/hip_bf16.h>
#include <math.h>

// ---------------------------------------------------------------------------
// MultiScaleGNN: 3x GAT (single head) -> BiLSTM JK attention -> linear out
// GAT: CSR (built once) + wave-per-dst aggregation, no atomics on hot path.
// LSTM: bf16 MFMA, weights LDS-resident, f32 nonlinearities.
// ---------------------------------------------------------------------------

typedef __attribute__((ext_vector_type(4))) float f32x4;
typedef __attribute__((ext_vector_type(8))) short bf16x8;

__device__ __forceinline__ float sigmoid_f(float x) {
    return 1.0f / (1.0f + __expf(-x));
}
__device__ __forceinline__ float tanh_f(float x) {
    return 2.0f / (1.0f + __expf(-2.0f * x)) - 1.0f;
}
__device__ __forceinline__ unsigned short f2bf(float x) {   // RNE f32->bf16
    union { float f; unsigned int u; } v; v.f = x;
    unsigned int r = (v.u + 0x7FFFu + ((v.u >> 16) & 1u)) >> 16;
    return (unsigned short)r;
}

// ---- GAT: h = x @ W^T ; al = h @ asrc ; ar = h @ adst  (one wave per node) --
template<int K>
__global__ __launch_bounds__(256) void lin_kernel(
    const float* __restrict__ x, const float* __restrict__ W,
    const float* __restrict__ asrc, const float* __restrict__ adst,
    float* __restrict__ h, float* __restrict__ al, float* __restrict__ ar, int N)
{
    __shared__ __align__(16) float Wl[64][K + 4];
    for (int i = threadIdx.x; i < 64 * K; i += 256)
        Wl[i / K][i % K] = W[i];
    __syncthreads();

    int lane = threadIdx.x & 63;
    float as = asrc[lane], ad = adst[lane];
    int wid = (blockIdx.x * 256 + threadIdx.x) >> 6;
    int nw  = (gridDim.x * 256) >> 6;
    for (int n = wid; n < N; n += nw) {
        int nu = __builtin_amdgcn_readfirstlane(n);
        const float* xr = x + (size_t)nu * K;
        float acc = 0.0f;
        #pragma unroll
        for (int k = 0; k < K; k += 4) {
            float4 xv = *reinterpret_cast<const float4*>(xr + k);
            f32x4 wv = *reinterpret_cast<const f32x4*>(&Wl[lane][k]);
            acc += xv.x * wv.x + xv.y * wv.y + xv.z * wv.z + xv.w * wv.w;
        }
        h[(size_t)nu * 64 + lane] = acc;
        float pa = acc * as, pr = acc * ad;
        #pragma unroll
        for (int off = 32; off > 0; off >>= 1) {
            pa += __shfl_down(pa, off);
            pr += __shfl_down(pr, off);
        }
        if (lane == 0) { al[nu] = pa; ar[nu] = pr; }
    }
}

// ============================ CSR build (once) =============================
__global__ void csr_zero(int* __restrict__ deg, int* __restrict__ cursor, int N)
{
    int i = blockIdx.x * blockDim.x + threadIdx.x;
    if (i < N) { deg[i] = 0; cursor[i] = 0; }
}

__global__ void csr_hist(const int* __restrict__ dst, int* __restrict__ deg, int E)
{
    int i = blockIdx.x * blockDim.x + threadIdx.x;
    if (i < E) atomicAdd(&deg[dst[i]], 1);
}

// inclusive scan of degp = deg+1 within 256-blocks; incl + per-block totals
__global__ void csr_scan1(const int* __restrict__ deg, int* __restrict__ incl,
                          int* __restrict__ part, int N)
{
    __shared__ int sb[2][256];
    int tid = threadIdx.x;
    int i = blockIdx.x * 256 + tid;
    int v = (i < N) ? deg[i] + 1 : 0;
    sb[0][tid] = v;
    __syncthreads();
    int cur = 0;
    #pragma unroll
    for (int off = 1; off < 256; off <<= 1) {
        int s = sb[cur][tid];
        if (tid >= off) s += sb[cur][tid - off];
        sb[cur ^ 1][tid] = s;
        cur ^= 1;
        __syncthreads();
    }
    if (i < N) incl[i] = sb[cur][tid];
    if (tid == 255) part[blockIdx.x] = sb[cur][255];
}

// exclusive scan of block totals (NB <= 256) in one block
__global__ void csr_scan2(int* __restrict__ part, int NB)
{
    __shared__ int sb[2][256];
    int tid = threadIdx.x;
    int v = (tid < NB) ? part[tid] : 0;
    sb[0][tid] = v;
    __syncthreads();
    int cur = 0;
    #pragma unroll
    for (int off = 1; off < 256; off <<= 1) {
        int s = sb[cur][tid];
        if (tid >= off) s += sb[cur][tid - off];
        sb[cur ^ 1][tid] = s;
        cur ^= 1;
        __syncthreads();
    }
    if (tid < NB) part[tid] = sb[cur][tid] - v;   // exclusive
}

__global__ void csr_scan3(const int* __restrict__ deg, const int* __restrict__ incl,
                          const int* __restrict__ part, int* __restrict__ rowptr,
                          int N, int total)
{
    int i = blockIdx.x * blockDim.x + threadIdx.x;
    if (i < N)
        rowptr[i] = part[i >> 8] + incl[i] - (deg[i] + 1);
    if (i == 0) rowptr[N] = total;
}

__global__ void csr_scatter(const int* __restrict__ src, const int* __restrict__ dst,
                            const int* __restrict__ rowptr, int* __restrict__ cursor,
                            int* __restrict__ csr_src, int E, int N)
{
    int i = blockIdx.x * blockDim.x + threadIdx.x;
    if (i >= E + N) return;
    int s = (i < E) ? src[i] : (i - E);
    int d = (i < E) ? dst[i] : (i - E);
    int pos = atomicAdd(&cursor[d], 1);
    csr_src[rowptr[d] + pos] = s;
}

// ---- per-dst aggregation: softmax-weighted neighbor sum, fused finalize ----
// one wave per dst; phase1: lanes over edges (ex, den); phase2: lanes over
// channels, shfl-broadcast (s, ex) per edge. No atomics.
__global__ __launch_bounds__(256) void agg_kernel(
    const int* __restrict__ rowptr, const int* __restrict__ csr_src,
    const float* __restrict__ al, const float* __restrict__ ar,
    const float* __restrict__ h, const float* __restrict__ b,
    float* __restrict__ outseq, int N)
{
    int lane = threadIdx.x & 63;
    int w = threadIdx.x >> 6;
    int d = blockIdx.x * 4 + w;
    if (d >= N) return;

    int rp0 = rowptr[d], rp1 = rowptr[d + 1];
    int degd = rp1 - rp0;
    float ard = ar[d];
    float den = 0.0f, acc = 0.0f;

    for (int c0 = 0; c0 < degd; c0 += 64) {
        int ne = min(64, degd - c0);
        int s_l = 0;
        float ex_l = 0.0f;
        if (lane < ne) {
            s_l = csr_src[rp0 + c0 + lane];
            float e = al[s_l] + ard;
            e = (e >= 0.0f) ? e : 0.2f * e;
            ex_l = __expf(e);
        }
        float dsum = ex_l;
        #pragma unroll
        for (int off = 32; off > 0; off >>= 1) dsum += __shfl_xor(dsum, off);
        den += dsum;
        #pragma unroll 4
        for (int e2 = 0; e2 < ne; ++e2) {
            float exb = __shfl(ex_l, e2);
            int sb = __shfl(s_l, e2);
            acc += exb * h[(size_t)sb * 64 + lane];
        }
    }
    float v = acc / den + b[lane];
    outseq[(size_t)d * 64 + lane] = fmaxf(v, 0.0f);
}

// ---- LSTM weight prep: bf16, FRAGMENT-LANE-MAJOR order --------------------
// Per dir (61440 bf16): Wih frags f=(q*6+t6)*2+kc (48), Whh frags at +24576,
// f=(q*6+t6)*3+kc (72). Each frag = 512 bf16: [lane][slot], lane=(g<<4)|i16,
// value = W[j = q*96+t6*16+i16][k = kc*32+g*8+slot].
__global__ void prep_lstm(
    const float* __restrict__ WihF, const float* __restrict__ WhhF,
    const float* __restrict__ bihF, const float* __restrict__ bhhF,
    const float* __restrict__ WihB_, const float* __restrict__ WhhB_,
    const float* __restrict__ bihB_, const float* __restrict__ bhhB_,
    unsigned short* __restrict__ WB, float* __restrict__ bsum)
{
    int tid = blockIdx.x * blockDim.x + threadIdx.x;
    if (tid < 2 * 61440) {
        int dir = tid / 61440, rr = tid % 61440;
        const float* Wih = dir ? WihB_ : WihF;
        const float* Whh = dir ? WhhB_ : WhhF;
        float v;
        if (rr < 24576) {
            int f = rr >> 9, l = (rr >> 3) & 63, s = rr & 7;
            int kc = f & 1, qt = f >> 1;
            int q = qt / 6, t6 = qt % 6;
            int j = q * 96 + t6 * 16 + (l & 15);
            int k = kc * 32 + (l >> 4) * 8 + s;
            v = Wih[j * 64 + k];
        } else {
            int rr2 = rr - 24576;
            int f = rr2 >> 9, l = (rr2 >> 3) & 63, s = rr2 & 7;
            int kc = f % 3, qt = f / 3;
            int q = qt / 6, t6 = qt % 6;
            int j = q * 96 + t6 * 16 + (l & 15);
            int k = kc * 32 + (l >> 4) * 8 + s;
            v = Whh[j * 96 + k];
        }
        WB[tid] = f2bf(v);
    } else if (tid < 2 * 61440 + 2 * 384) {
        int q2 = tid - 2 * 61440;
        int dir = q2 / 384, j = q2 % 384;
        bsum[q2] = dir ? (bihB_[j] + bhhB_[j]) : (bihF[j] + bhhF[j]);
    }
}

// ---- fused BiLSTM (MFMA, LDS weights) + JK attention + out projection -----
// LDS map (shorts): [0,61440) W frags; [61440,75264) xs stride 72 (pads hold
// logits); [75264,81920) hs stride 104. 160 KB, 1 block/CU -> all latency
// hiding must come from ILP: no sched_barriers, let the compiler pipeline.
__global__ __launch_bounds__(256, 1) void lstm_kernel(
    const float* __restrict__ seq, const unsigned short* __restrict__ WB,
    const float* __restrict__ bsum, const float* __restrict__ attW,
    const float* __restrict__ attb, const float* __restrict__ outW,
    const float* __restrict__ outb, float* __restrict__ out, int N)
{
    __shared__ __align__(16) unsigned short smem[81920];
    unsigned short* WL = smem;
    unsigned short* XS = smem + 61440;
    unsigned short* HS = smem + 75264;

    const int tid  = threadIdx.x;
    const int lane = tid & 63;
    const int w    = tid >> 6;
    const int i16  = lane & 15;
    const int g    = lane >> 4;
    const int n0   = blockIdx.x * 64;
    const int nodebase = 16 * w;
    const int myrow = nodebase + g * 4;

    // stage xs (float4 -> 4x bf16) + logits (attb) in xs row-pads
    for (int idx = tid; idx < 3 * 64 * 16; idx += 256) {
        int t = idx >> 10, r = (idx >> 4) & 63, k4 = idx & 15;
        int n = n0 + r;
        float4 v = (n < N)
            ? *reinterpret_cast<const float4*>(&seq[((size_t)t * N + n) * 64 + k4 * 4])
            : make_float4(0.f, 0.f, 0.f, 0.f);
        ushort2 lo = {f2bf(v.x), f2bf(v.y)};
        ushort2 hi = {f2bf(v.z), f2bf(v.w)};
        unsigned short* p = &XS[(t * 64 + r) * 72 + k4 * 4];
        *reinterpret_cast<ushort2*>(p) = lo;
        *reinterpret_cast<ushort2*>(p + 2) = hi;
    }
    float attb0 = attb[0];
    if (tid < 192)
        *reinterpret_cast<float*>(&XS[tid * 72 + 64]) = attb0;

    for (int dir = 0; dir < 2; ++dir) {
        __syncthreads();   // xs staged / previous dir's W reads complete
        {   // stage this dir's 120 KB of weight fragments (linear, b128)
            const f32x4* gsrc = reinterpret_cast<const f32x4*>(WB + dir * 61440);
            f32x4* ldst = reinterpret_cast<f32x4*>(WL);
            #pragma unroll
            for (int it = 0; it < 30; ++it)
                ldst[it * 256 + tid] = gsrc[it * 256 + tid];
        }
        // zero this wave's hs rows (wave-private)
        for (int e2 = lane; e2 < 16 * 48; e2 += 64) {
            int r = e2 / 48, c2 = e2 % 48;
            *reinterpret_cast<unsigned int*>(&HS[(nodebase + r) * 104 + c2 * 2]) = 0u;
        }
        const float* bs = bsum + dir * 384;
        const float* aw = attW + dir * 96;
        float bsr[24];
        #pragma unroll
        for (int t6 = 0; t6 < 6; ++t6)
            #pragma unroll
            for (int q = 0; q < 4; ++q)
                bsr[t6 * 4 + q] = bs[q * 96 + t6 * 16 + i16];
        float awr[6];
        #pragma unroll
        for (int t6 = 0; t6 < 6; ++t6) awr[t6] = aw[t6 * 16 + i16];
        float c[24];
        #pragma unroll
        for (int a = 0; a < 24; ++a) c[a] = 0.0f;
        __syncthreads();   // WL visible

        for (int step = 0; step < 3; ++step) {
            int t = dir ? (2 - step) : step;
            const unsigned short* xrow = &XS[((t * 64 + nodebase + i16) * 72)];
            bf16x8 ax0 = *reinterpret_cast<const bf16x8*>(xrow + g * 8);
            bf16x8 ax1 = *reinterpret_cast<const bf16x8*>(xrow + 32 + g * 8);
            const unsigned short* hrow = &HS[(nodebase + i16) * 104];
            bf16x8 ah0 = *reinterpret_cast<const bf16x8*>(hrow + g * 8);
            bf16x8 ah1 = *reinterpret_cast<const bf16x8*>(hrow + 32 + g * 8);
            bf16x8 ah2 = *reinterpret_cast<const bf16x8*>(hrow + 64 + g * 8);
            const unsigned short* wbase = WL + lane * 8;

            float lp[4] = {0.0f, 0.0f, 0.0f, 0.0f};
            #pragma unroll
            for (int t6 = 0; t6 < 6; ++t6) {
                const int jb = t6 * 16 + i16;
                f32x4 acc4[4];
                #pragma unroll
                for (int q = 0; q < 4; ++q) {
                    float bv = bsr[t6 * 4 + q];
                    acc4[q] = (f32x4){bv, bv, bv, bv};
                }
                #pragma unroll
                for (int q = 0; q < 4; ++q) {
                    const int qt = q * 6 + t6;
                    const unsigned short* wih = wbase + (qt * 2) * 512;
                    const unsigned short* whh = wbase + 24576 + (qt * 3) * 512;
                    acc4[q] = __builtin_amdgcn_mfma_f32_16x16x32_bf16(
                        ax0, *reinterpret_cast<const bf16x8*>(wih), acc4[q], 0, 0, 0);
                    acc4[q] = __builtin_amdgcn_mfma_f32_16x16x32_bf16(
                        ax1, *reinterpret_cast<const bf16x8*>(wih + 512), acc4[q], 0, 0, 0);
                    acc4[q] = __builtin_amdgcn_mfma_f32_16x16x32_bf16(
                        ah0, *reinterpret_cast<const bf16x8*>(whh), acc4[q], 0, 0, 0);
                    acc4[q] = __builtin_amdgcn_mfma_f32_16x16x32_bf16(
                        ah1, *reinterpret_cast<const bf16x8*>(whh + 512), acc4[q], 0, 0, 0);
                    acc4[q] = __builtin_amdgcn_mfma_f32_16x16x32_bf16(
                        ah2, *reinterpret_cast<const bf16x8*>(whh + 1024), acc4[q], 0, 0, 0);
                }
                #pragma unroll
                for (int reg = 0; reg < 4; ++reg) {
                    float ii = acc4[0][reg];
                    float ff = acc4[1][reg];
                    float gg = acc4[2][reg];
                    float oo = acc4[3][reg];
                    float cn = sigmoid_f(ff) * c[t6 * 4 + reg]
                             + sigmoid_f(ii) * tanh_f(gg);
                    c[t6 * 4 + reg] = cn;
                    float hn = sigmoid_f(oo) * tanh_f(cn);
                    HS[(myrow + reg) * 104 + jb] = f2bf(hn);
                    lp[reg] += hn * awr[t6];
                }
            }
            #pragma unroll
            for (int reg = 0; reg < 4; ++reg) {
                float v = lp[reg];
                v += __shfl_xor(v, 1);
                v += __shfl_xor(v, 2);
                v += __shfl_xor(v, 4);
                v += __shfl_xor(v, 8);
                if (i16 == 0)
                    *reinterpret_cast<float*>(
                        &XS[(t * 64 + myrow + reg) * 72 + 64]) += v;
            }
        }
    }
    __syncthreads();

    // alpha = softmax over the 3 layers (logits live in xs pads)
    float* alphaF = reinterpret_cast<float*>(HS);   // hs is dead now
    if (w == 0) {
        float l0 = *reinterpret_cast<float*>(&XS[(0 * 64 + lane) * 72 + 64]);
        float l1 = *reinterpret_cast<float*>(&XS[(1 * 64 + lane) * 72 + 64]);
        float l2 = *reinterpret_cast<float*>(&XS[(2 * 64 + lane) * 72 + 64]);
        float mx = fmaxf(fmaxf(l0, l1), l2);
        float e0 = __expf(l0 - mx), e1 = __expf(l1 - mx), e2 = __expf(l2 - mx);
        float inv = 1.0f / (e0 + e1 + e2);
        alphaF[lane] = e0 * inv; alphaF[64 + lane] = e1 * inv;
        alphaF[128 + lane] = e2 * inv;
    }
    __syncthreads();

    // agg[n][k] = sum_t alpha[t][n] * seq_f32[t][n][k]  (overwrites xs)
    float* aggF = reinterpret_cast<float*>(XS);     // stride 68 floats
    for (int idx = tid; idx < 64 * 64; idx += 256) {
        int r = idx >> 6, k = idx & 63;
        int n = n0 + r;
        float v = 0.0f;
        if (n < N) {
            float a0 = alphaF[r], a1 = alphaF[64 + r], a2 = alphaF[128 + r];
            v = a0 * seq[((size_t)n) * 64 + k]
              + a1 * seq[((size_t)N + n) * 64 + k]
              + a2 * seq[((size_t)2 * N + n) * 64 + k];
        }
        aggF[r * 68 + k] = v;
    }
    __syncthreads();

    // out[n][j] = agg[n] . outW[j] + outb[j]; outW row held in 64 VGPRs
    f32x4 ow[16];
    #pragma unroll
    for (int kk = 0; kk < 16; ++kk)
        ow[kk] = *reinterpret_cast<const f32x4*>(&outW[(size_t)lane * 64 + kk * 4]);
    float ob = outb[lane];
    for (int r = w; r < 64; r += 4) {
        int n = n0 + r;
        if (n >= N) break;
        float a = ob;
        #pragma unroll
        for (int kk = 0; kk < 16; ++kk) {
            f32x4 av = *reinterpret_cast<const f32x4*>(&aggF[r * 68 + kk * 4]);
            a += ow[kk].x * av.x + ow[kk].y * av.y
               + ow[kk].z * av.z + ow[kk].w * av.w;
        }
        out[(size_t)n * 64 + lane] = a;
    }
}

// ---------------------------------------------------------------------------
extern "C" void kernel_launch(void* const* d_in, const int* in_sizes, int n_in,
                              void* d_out, int out_size, void* d_ws, size_t ws_size,
                              hipStream_t stream)
{
    const float* x    = (const float*)d_in[0];
    const int*   ei   = (const int*)d_in[1];
    const float* convW[3]  = {(const float*)d_in[2], (const float*)d_in[6],  (const float*)d_in[10]};
    const float* convAs[3] = {(const float*)d_in[3], (const float*)d_in[7],  (const float*)d_in[11]};
    const float* convAd[3] = {(const float*)d_in[4], (const float*)d_in[8],  (const float*)d_in[12]};
    const float* convB[3]  = {(const float*)d_in[5], (const float*)d_in[9],  (const float*)d_in[13]};
    const float* WihF = (const float*)d_in[14];
    const float* WhhF = (const float*)d_in[15];
    const float* bihF = (const float*)d_in[16];
    const float* bhhF = (const float*)d_in[17];
    const float* WihB = (const float*)d_in[18];
    const float* WhhB = (const float*)d_in[19];
    const float* bihB = (const float*)d_in[20];
    const float* bhhB = (const float*)d_in[21];
    const float* attW = (const float*)d_in[22];
    const float* attb = (const float*)d_in[23];
    const float* outW = (const float*)d_in[24];
    const float* outb = (const float*)d_in[25];

    int N = in_sizes[0] / 128;
    int E = in_sizes[1] / 2;
    const int* src = ei;
    const int* dst = ei + E;
    int total = E + N;

    float* w = (float*)d_ws;
    float* seq  = w;  w += (size_t)3 * N * 64;
    float* h_ws = w;  w += (size_t)N * 64;
    float* al   = w;  w += N;
    float* ar   = w;  w += N;
    float* bsum = w;  w += 768;
    unsigned short* WB = (unsigned short*)w;  w += 61440;   // 122880 bf16
    int* deg     = (int*)w;        w += N;
    int* cursor  = (int*)w;        w += N;
    int* rowptr  = (int*)w;        w += (N + 1);
    int* incl    = (int*)w;        w += N;
    int* part    = (int*)w;        w += 256;
    int* csr_src = (int*)w;        w += total;

    int NB = (N + 255) / 256;

    // CSR build (graph is layer-invariant)
    csr_zero<<<NB, 256, 0, stream>>>(deg, cursor, N);
    csr_hist<<<(E + 255) / 256, 256, 0, stream>>>(dst, deg, E);
    csr_scan1<<<NB, 256, 0, stream>>>(deg, incl, part, N);
    csr_scan2<<<1, 256, 0, stream>>>(part, NB);
    csr_scan3<<<NB, 256, 0, stream>>>(deg, incl, part, rowptr, N, total);
    csr_scatter<<<(total + 255) / 256, 256, 0, stream>>>(src, dst, rowptr, cursor,
                                                         csr_src, E, N);

    prep_lstm<<<(2 * 61440 + 768 + 255) / 256, 256, 0, stream>>>(
        WihF, WhhF, bihF, bhhF, WihB, WhhB, bihB, bhhB, WB, bsum);

    for (int l = 0; l < 3; ++l) {
        const float* in = (l == 0) ? x : seq + (size_t)(l - 1) * N * 64;
        if (l == 0)
            lin_kernel<128><<<2048, 256, 0, stream>>>(in, convW[l], convAs[l], convAd[l],
                                                      h_ws, al, ar, N);
        else
            lin_kernel<64><<<2048, 256, 0, stream>>>(in, convW[l], convAs[l], convAd[l],
                                                     h_ws, al, ar, N);
        agg_kernel<<<(N + 3) / 4, 256, 0, stream>>>(rowptr, csr_src, al, ar, h_ws,
                                                    convB[l], seq + (size_t)l * N * 64, N);
    }

    lstm_kernel<<<(N + 63) / 64, 256, 0, stream>>>(seq, WB, bsum, attW, attb,
                                                   outW, outb, (float*)d_out, N);
}